// Round 6
// baseline (397.371 us; speedup 1.0000x reference)
//
#include <hip/hip_runtime.h>
#include <stdint.h>

#define MDIM 8192
#define NDIM 4096
#define KDIM 4096

typedef float accf_t __attribute__((ext_vector_type(4)));
typedef short s16x8 __attribute__((ext_vector_type(8)));

typedef const __attribute__((address_space(1))) uint8_t* gas_t;
typedef __attribute__((address_space(3))) uint8_t* las_t;

__device__ __forceinline__ void gload16(const void* g, void* l) {
  __builtin_amdgcn_global_load_lds((gas_t)g, (las_t)l, 16, 0, 0);
}

// round-to-nearest-even f32 -> bf16, packed pair
__device__ __forceinline__ uint32_t pk_bf16(float a, float b) {
  uint32_t ua = __builtin_bit_cast(uint32_t, a);
  uint32_t ub = __builtin_bit_cast(uint32_t, b);
  ua += 0x7fffu + ((ua >> 16) & 1u);
  ub += 0x7fffu + ((ub >> 16) & 1u);
  return (ua >> 16) | (ub & 0xffff0000u);
}

// ---------------- prepass: x (f32) -> bf16 ----------------
__global__ void cvt_x_kernel(const float* __restrict__ x, uint16_t* __restrict__ xb) {
  int64_t e = ((int64_t)blockIdx.x * 256 + threadIdx.x) * 8;
  float4 f0 = *reinterpret_cast<const float4*>(x + e);
  float4 f1 = *reinterpret_cast<const float4*>(x + e + 4);
  uint4 u;
  u.x = pk_bf16(f0.x, f0.y);
  u.y = pk_bf16(f0.z, f0.w);
  u.z = pk_bf16(f1.x, f1.y);
  u.w = pk_bf16(f1.z, f1.w);
  *reinterpret_cast<uint4*>(xb + e) = u;
}

// ---------------- prepass: build W^T bf16 [N][K] with Hamilton signs ----------------
__global__ void build_wt_kernel(const float* __restrict__ Wr, const float* __restrict__ Wi,
                                const float* __restrict__ Wj, const float* __restrict__ Wk,
                                uint16_t* __restrict__ wt) {
  __shared__ float t[64][65];
  const int k0 = blockIdx.x * 64;
  const int n0 = blockIdx.y * 64;
  const int rc = k0 >> 10, cc = n0 >> 10;
  const int srcsel[16] = {0,1,2,3, 1,0,3,2, 2,3,0,1, 3,2,1,0};
  const float sgntab[16] = {1.f,1.f,1.f,1.f, -1.f,1.f,1.f,-1.f, -1.f,-1.f,1.f,1.f, -1.f,1.f,-1.f,1.f};
  const float* srcs[4] = {Wr, Wi, Wj, Wk};
  const float* W = srcs[srcsel[rc * 4 + cc]];
  const float sg = sgntab[rc * 4 + cc];
  const int kq0 = k0 & 1023, nq0 = n0 & 1023;
  const int tid = threadIdx.x;
  const int lr = tid >> 6;
  const int lc = tid & 63;
#pragma unroll
  for (int p = 0; p < 16; ++p) {
    int kl = p * 4 + lr;
    t[kl][lc] = W[(int64_t)(kq0 + kl) * 1024 + nq0 + lc];
  }
  __syncthreads();
  const int kb = (tid & 7) * 8;
#pragma unroll
  for (int p = 0; p < 2; ++p) {
    int nl = p * 32 + (tid >> 3);
    uint4 u;
    u.x = pk_bf16(sg * t[kb + 0][nl], sg * t[kb + 1][nl]);
    u.y = pk_bf16(sg * t[kb + 2][nl], sg * t[kb + 3][nl]);
    u.z = pk_bf16(sg * t[kb + 4][nl], sg * t[kb + 5][nl]);
    u.w = pk_bf16(sg * t[kb + 6][nl], sg * t[kb + 7][nl]);
    *reinterpret_cast<uint4*>(wt + (int64_t)(n0 + nl) * KDIM + k0 + kb) = u;
  }
}

// ================= v6: 256x256, B in registers, A-only LDS =================
// 8 waves 2Mx4N, per-wave C 128x64 (8x4 16x16x32 frags), BK=64.
// LDS: A only, 2 bufs x 32KB ([256 rows][8 chunks of 16B], phys chunk =
//   logical ^ (row&7); linear gload_lds dest + pre-swizzled global source).
// B: direct global->VGPR via inline-asm global_load_dwordx4, double-buffered
//   (bA/bB), depth-1 K-tile prefetch (L2/LLC-resident panel).
// Sync per K-tile: [issue B(t+1)+A(t+1) (12 loads)] [vmcnt(12) == exactly the
//   just-issued 12 => tile t fully confirmed] [barrier] [4 MFMA phases, NO
//   barriers, waves skew -> LDS/MFMA pipes overlap across waves] [barrier
//   (WAR: buf parity t+2 == t is re-written only after this)].

#define SB __builtin_amdgcn_sched_barrier(0);
#define BAR __builtin_amdgcn_s_barrier();

#define BLOAD2(d0, d1, p)                                                     \
  asm volatile("global_load_dwordx4 %0, %2, off\n\t"                          \
               "global_load_dwordx4 %1, %2, off offset:64"                    \
               : "=&v"(d0), "=&v"(d1) : "v"(p));

// Issue staging for one tile into parity P: 8 B-loads (-> BD) + 4 A gload_lds.
#define ISSUE_T(P, BD) {                                                      \
    BLOAD2(BD[0][0], BD[0][1], pB0); pB0 += 128;                              \
    BLOAD2(BD[1][0], BD[1][1], pB1); pB1 += 128;                              \
    BLOAD2(BD[2][0], BD[2][1], pB2); pB2 += 128;                              \
    BLOAD2(BD[3][0], BD[3][1], pB3); pB3 += 128;                              \
    gload16(aS0, dstW + (P) * 32768);         aS0 += 64;                      \
    gload16(aS1, dstW + (P) * 32768 +  8192); aS1 += 64;                      \
    gload16(aS2, dstW + (P) * 32768 + 16384); aS2 += 64;                      \
    gload16(aS3, dstW + (P) * 32768 + 24576); aS3 += 64; }

#define WAITV(N) { SB asm volatile("s_waitcnt vmcnt(" #N ")"); SB }

// Compute one K-tile from A-buf parity P and B regs BD. No internal barriers.
#define COMPUTE(P, BD)                                                        \
  _Pragma("unroll")                                                           \
  for (int kh = 0; kh < 2; ++kh) {                                            \
    _Pragma("unroll")                                                         \
    for (int mh = 0; mh < 2; ++mh) {                                          \
      s16x8 afr[4];                                                           \
      _Pragma("unroll")                                                       \
      for (int f = 0; f < 4; ++f)                                             \
        afr[f] = *(const s16x8*)(Abuf + (P) * 32768 + (aoff[mh * 4 + f] ^ (kh * 64))); \
      __builtin_amdgcn_s_setprio(1);                                          \
      _Pragma("unroll")                                                       \
      for (int f = 0; f < 4; ++f)                                             \
        _Pragma("unroll")                                                     \
        for (int fn = 0; fn < 4; ++fn)                                        \
          acc[mh * 4 + f][fn] = __builtin_amdgcn_mfma_f32_16x16x32_bf16(      \
              afr[f], BD[fn][kh], acc[mh * 4 + f][fn], 0, 0, 0);              \
      __builtin_amdgcn_s_setprio(0);                                          \
    }                                                                         \
  }

__global__ __launch_bounds__(512, 2)
void qgemm9_kernel(const uint16_t* __restrict__ xb, const uint16_t* __restrict__ wt,
                   const float* __restrict__ br, const float* __restrict__ bi,
                   const float* __restrict__ bj, const float* __restrict__ bk,
                   float* __restrict__ out) {
  __shared__ __align__(16) uint8_t Abuf[65536];
  const int tid = threadIdx.x;
  const int wid = tid >> 6, lane = tid & 63;
  const int kg = lane >> 4, rl = lane & 15;
  const int wm = wid >> 2, wn = wid & 3;

  // XCD-aware bijective swizzle (512 blocks % 8 == 0)
  const int bid = blockIdx.x;
  const int swz = (bid & 7) * 64 + (bid >> 3);
  const int tn = swz >> 5, tm = swz & 31;
  const int m0 = tm * 256, n0 = tn * 256;

  // ---- A staging (linear LDS dest, pre-swizzled global source) ----
  // dest byte D = 16*(j*512+tid): row = j*64 + (tid>>3), phys chunk = tid&7
  // logical chunk g = (tid&7) ^ (row&7); (row&7) is j-invariant.
  const int arow0 = tid >> 3;
  const int gch = (tid & 7) ^ (arow0 & 7);
  const uint16_t* aS0 = xb + (int64_t)(m0 + arow0) * KDIM + gch * 8;
  const uint16_t* aS1 = xb + (int64_t)(m0 + arow0 + 64) * KDIM + gch * 8;
  const uint16_t* aS2 = xb + (int64_t)(m0 + arow0 + 128) * KDIM + gch * 8;
  const uint16_t* aS3 = xb + (int64_t)(m0 + arow0 + 192) * KDIM + gch * 8;
  uint8_t* dstW = Abuf + wid * 1024;  // wave-uniform; HW appends lane*16

  // ---- B direct-load pointers (per lane; f covers n-frag, offset:64 covers kh) ----
  const uint8_t* pB0 = (const uint8_t*)wt + (int64_t)(n0 + wn * 64 + 0 + rl) * (KDIM * 2) + kg * 16;
  const uint8_t* pB1 = (const uint8_t*)wt + (int64_t)(n0 + wn * 64 + 16 + rl) * (KDIM * 2) + kg * 16;
  const uint8_t* pB2 = (const uint8_t*)wt + (int64_t)(n0 + wn * 64 + 32 + rl) * (KDIM * 2) + kg * 16;
  const uint8_t* pB3 = (const uint8_t*)wt + (int64_t)(n0 + wn * 64 + 48 + rl) * (KDIM * 2) + kg * 16;

  // ---- A fragment read offsets (kh=0; kh=1 is ^64) ----
  int aoff[8];
#pragma unroll
  for (int q = 0; q < 8; ++q) {
    int r = wm * 128 + q * 16 + rl;  // q = mh*4+f
    aoff[q] = r * 128 + ((kg ^ (r & 7)) << 4);
  }

  accf_t acc[8][4] = {};
  s16x8 bA[4][2], bB[4][2];

  // prologue: tile 0 -> buf0/bA
  ISSUE_T(0, bA)

  for (int i = 0; i < 31; ++i) {
    // even tile t=2i: issue t+1 -> buf1/bB; compute buf0/bA
    ISSUE_T(1, bB)
    WAITV(12)
    BAR
    COMPUTE(0, bA)
    BAR
    // odd tile t+1: issue t+2 -> buf0/bA; compute buf1/bB
    ISSUE_T(0, bA)
    WAITV(12)
    BAR
    COMPUTE(1, bB)
    BAR
  }
  // tile 62 (buf0/bA), issuing 63 -> buf1/bB
  ISSUE_T(1, bB)
  WAITV(12)
  BAR
  COMPUTE(0, bA)
  BAR
  // tile 63 (buf1/bB), nothing left to issue
  WAITV(0)
  BAR
  COMPUTE(1, bB)

  // epilogue: Hamilton bias + f32 store
  const float s_i[4] = {-1.f, 1.f, -1.f, 1.f};
  const float s_j[4] = {-1.f, 1.f, 1.f, -1.f};
  const float s_k[4] = {-1.f, -1.f, 1.f, 1.f};
  float bias[4];
#pragma unroll
  for (int fn = 0; fn < 4; ++fn) {
    int col = n0 + wn * 64 + fn * 16 + rl;
    int cc = col >> 10, nq = col & 1023;
    bias[fn] = br[nq] + s_i[cc] * bi[nq] + s_j[cc] * bj[nq] + s_k[cc] * bk[nq];
  }
#pragma unroll
  for (int fm = 0; fm < 8; ++fm) {
    int rowb = m0 + wm * 128 + fm * 16 + kg * 4;
#pragma unroll
    for (int r = 0; r < 4; ++r) {
      float* op = out + (int64_t)(rowb + r) * NDIM + n0 + wn * 64 + rl;
#pragma unroll
      for (int fn = 0; fn < 4; ++fn)
        op[fn * 16] = acc[fm][fn][r] + bias[fn];
    }
  }
}

// ---------------- fallback: R1 128x128 m97-structure GEMM ----------------
template <int AWS>
__global__ __launch_bounds__(256, 3)
void qgemm_kernel(const uint16_t* __restrict__ xb, const float* __restrict__ xf,
                  const uint16_t* __restrict__ wt,
                  const float* __restrict__ br, const float* __restrict__ bi,
                  const float* __restrict__ bj, const float* __restrict__ bk,
                  float* __restrict__ out) {
  __shared__ __align__(16) uint16_t Alds[128 * 32];
  __shared__ __align__(16) uint16_t Blds[128 * 32];
  const int tid = threadIdx.x;
  const int wid = tid >> 6, lane = tid & 63;
  const int kg = lane >> 4, rl = lane & 15;
  const int bid = blockIdx.x;
  const int swz = (bid & 7) * 256 + (bid >> 3);
  const int tile_m = swz & 63;
  const int tile_n = swz >> 6;
  const int m0 = tile_m * 128, n0 = tile_n * 128;
  const int wr = wid >> 1, wc = wid & 1;
  const int e0 = tid * 8, e1 = (256 + tid) * 8;
  const int r0 = e0 >> 5, r1 = e1 >> 5;
  const int s0 = (e0 >> 3) & 3, s1 = (e1 >> 3) & 3;
  const int g0 = s0 ^ ((r0 >> 1) & 3);
  const int g1 = s1 ^ ((r1 >> 1) & 3);
  const uint16_t* bp0 = wt + (int64_t)(n0 + r0) * KDIM + g0 * 8;
  const uint16_t* bp1 = wt + (int64_t)(n0 + r1) * KDIM + g1 * 8;
  const uint16_t* ap0 = nullptr;
  const uint16_t* ap1 = nullptr;
  const float* af0 = nullptr;
  const float* af1 = nullptr;
  if (AWS) {
    ap0 = xb + (int64_t)(m0 + r0) * KDIM + g0 * 8;
    ap1 = xb + (int64_t)(m0 + r1) * KDIM + g1 * 8;
  } else {
    af0 = xf + (int64_t)(m0 + r0) * KDIM + g0 * 8;
    af1 = xf + (int64_t)(m0 + r1) * KDIM + g1 * 8;
  }
  uint8_t* Ab = (uint8_t*)Alds;
  uint8_t* Bb = (uint8_t*)Blds;
  uint8_t* AbW0 = Ab + wid * 1024;
  uint8_t* AbW1 = Ab + 4096 + wid * 1024;
  uint8_t* BbW0 = Bb + wid * 1024;
  uint8_t* BbW1 = Bb + 4096 + wid * 1024;
  uint8_t* aw0 = Ab + e0 * 2;
  uint8_t* aw1 = Ab + e1 * 2;
  int aoff[4], boff[4];
#pragma unroll
  for (int f = 0; f < 4; ++f) {
    int arow = wr * 64 + f * 16 + rl;
    aoff[f] = arow * 64 + ((kg ^ ((arow >> 1) & 3)) << 4);
    int bcol = wc * 64 + f * 16 + rl;
    boff[f] = bcol * 64 + ((kg ^ ((bcol >> 1) & 3)) << 4);
  }
  accf_t acc[4][4] = {};
  for (int kt = 0; kt < KDIM / 32; ++kt) {
    gload16(bp0, BbW0);
    gload16(bp1, BbW1);
    bp0 += 32; bp1 += 32;
    if (AWS) {
      gload16(ap0, AbW0);
      gload16(ap1, AbW1);
      ap0 += 32; ap1 += 32;
    } else {
      float4 fa = *reinterpret_cast<const float4*>(af0);
      float4 fb = *reinterpret_cast<const float4*>(af0 + 4);
      float4 fc = *reinterpret_cast<const float4*>(af1);
      float4 fd = *reinterpret_cast<const float4*>(af1 + 4);
      uint4 u0, u1;
      u0.x = pk_bf16(fa.x, fa.y); u0.y = pk_bf16(fa.z, fa.w);
      u0.z = pk_bf16(fb.x, fb.y); u0.w = pk_bf16(fb.z, fb.w);
      u1.x = pk_bf16(fc.x, fc.y); u1.y = pk_bf16(fc.z, fc.w);
      u1.z = pk_bf16(fd.x, fd.y); u1.w = pk_bf16(fd.z, fd.w);
      *reinterpret_cast<uint4*>(aw0) = u0;
      *reinterpret_cast<uint4*>(aw1) = u1;
      af0 += 32; af1 += 32;
    }
    __syncthreads();
    s16x8 afr[4], bfr[4];
#pragma unroll
    for (int f = 0; f < 4; ++f) afr[f] = *reinterpret_cast<const s16x8*>(Ab + aoff[f]);
#pragma unroll
    for (int f = 0; f < 4; ++f) bfr[f] = *reinterpret_cast<const s16x8*>(Bb + boff[f]);
#pragma unroll
    for (int fm = 0; fm < 4; ++fm)
#pragma unroll
      for (int fn = 0; fn < 4; ++fn)
        acc[fm][fn] = __builtin_amdgcn_mfma_f32_16x16x32_bf16(afr[fm], bfr[fn], acc[fm][fn], 0, 0, 0);
    __syncthreads();
  }
  const float s_i[4] = {-1.f, 1.f, -1.f, 1.f};
  const float s_j[4] = {-1.f, 1.f, 1.f, -1.f};
  const float s_k[4] = {-1.f, -1.f, 1.f, 1.f};
  float bias[4];
#pragma unroll
  for (int fn = 0; fn < 4; ++fn) {
    int col = n0 + wc * 64 + fn * 16 + rl;
    int cc = col >> 10, nq = col & 1023;
    bias[fn] = br[nq] + s_i[cc] * bi[nq] + s_j[cc] * bj[nq] + s_k[cc] * bk[nq];
  }
#pragma unroll
  for (int fm = 0; fm < 4; ++fm) {
    int rowb = m0 + wr * 64 + fm * 16 + kg * 4;
#pragma unroll
    for (int r = 0; r < 4; ++r) {
      float* op = out + (int64_t)(rowb + r) * NDIM + n0 + wc * 64 + rl;
#pragma unroll
      for (int fn = 0; fn < 4; ++fn)
        op[fn * 16] = acc[fm][fn][r] + bias[fn];
    }
  }
}

// ---------------- emergency fallback (ws too small): naive f32 ----------------
__global__ void naive_q_kernel(const float* __restrict__ x,
                               const float* __restrict__ Wr, const float* __restrict__ Wi,
                               const float* __restrict__ Wj, const float* __restrict__ Wk,
                               const float* __restrict__ br, const float* __restrict__ bi,
                               const float* __restrict__ bj, const float* __restrict__ bk,
                               float* __restrict__ out) {
  const int n = blockIdx.x * 256 + threadIdx.x;
  const int m = blockIdx.y;
  const int cc = n >> 10, nq = n & 1023;
  const int srcsel[16] = {0,1,2,3, 1,0,3,2, 2,3,0,1, 3,2,1,0};
  const float sgntab[16] = {1.f,1.f,1.f,1.f, -1.f,1.f,1.f,-1.f, -1.f,-1.f,1.f,1.f, -1.f,1.f,-1.f,1.f};
  const float s_i[4] = {-1.f,1.f,-1.f,1.f}, s_j[4] = {-1.f,1.f,1.f,-1.f}, s_k[4] = {-1.f,-1.f,1.f,1.f};
  const float* srcs[4] = {Wr, Wi, Wj, Wk};
  float acc = br[nq] + s_i[cc] * bi[nq] + s_j[cc] * bj[nq] + s_k[cc] * bk[nq];
  for (int rc = 0; rc < 4; ++rc) {
    const float* W = srcs[srcsel[rc * 4 + cc]];
    const float sg = sgntab[rc * 4 + cc];
    const float* xp = x + (int64_t)m * KDIM + rc * 1024;
    const float* wp = W + nq;
    float a = 0.f;
    for (int kq = 0; kq < 1024; ++kq) a = fmaf(xp[kq], wp[(int64_t)kq * 1024], a);
    acc += sg * a;
  }
  out[(int64_t)m * NDIM + n] = acc;
}

extern "C" void kernel_launch(void* const* d_in, const int* in_sizes, int n_in,
                              void* d_out, int out_size, void* d_ws, size_t ws_size,
                              hipStream_t stream) {
  const float* x  = (const float*)d_in[0];
  const float* Wr = (const float*)d_in[1];
  const float* Wi = (const float*)d_in[2];
  const float* Wj = (const float*)d_in[3];
  const float* Wk = (const float*)d_in[4];
  const float* br = (const float*)d_in[5];
  const float* bi = (const float*)d_in[6];
  const float* bj = (const float*)d_in[7];
  const float* bk = (const float*)d_in[8];
  float* out = (float*)d_out;

  const size_t WT_BYTES = (size_t)NDIM * KDIM * 2;  // 33.5 MB
  const size_t XB_BYTES = (size_t)MDIM * KDIM * 2;  // 67 MB

  if (ws_size < WT_BYTES) {
    dim3 g(NDIM / 256, MDIM);
    naive_q_kernel<<<g, 256, 0, stream>>>(x, Wr, Wi, Wj, Wk, br, bi, bj, bk, out);
    return;
  }
  uint16_t* wt = (uint16_t*)d_ws;
  build_wt_kernel<<<dim3(64, 64), 256, 0, stream>>>(Wr, Wi, Wj, Wk, wt);
  if (ws_size >= WT_BYTES + XB_BYTES) {
    uint16_t* xbp = wt + (size_t)NDIM * KDIM;
    cvt_x_kernel<<<(MDIM * (KDIM / 8)) / 256, 256, 0, stream>>>(x, xbp);
    qgemm9_kernel<<<512, 512, 0, stream>>>(xbp, wt, br, bi, bj, bk, out);
  } else {
    qgemm_kernel<0><<<2048, 256, 0, stream>>>(nullptr, x, wt, br, bi, bj, bk, out);
  }
}

// Round 7
// 319.400 us; speedup vs baseline: 1.2441x; 1.2441x over previous
//
#include <hip/hip_runtime.h>
#include <stdint.h>

#define MDIM 8192
#define NDIM 4096
#define KDIM 4096

typedef float accf_t __attribute__((ext_vector_type(4)));
typedef short s16x8 __attribute__((ext_vector_type(8)));

typedef const __attribute__((address_space(1))) uint8_t* gas_t;
typedef __attribute__((address_space(3))) uint8_t* las_t;

__device__ __forceinline__ void gload16(const void* g, void* l) {
  __builtin_amdgcn_global_load_lds((gas_t)g, (las_t)l, 16, 0, 0);
}

// round-to-nearest-even f32 -> bf16, packed pair
__device__ __forceinline__ uint32_t pk_bf16(float a, float b) {
  uint32_t ua = __builtin_bit_cast(uint32_t, a);
  uint32_t ub = __builtin_bit_cast(uint32_t, b);
  ua += 0x7fffu + ((ua >> 16) & 1u);
  ub += 0x7fffu + ((ub >> 16) & 1u);
  return (ua >> 16) | (ub & 0xffff0000u);
}

__device__ __forceinline__ uint16_t bf16_1(float a) {
  uint32_t ua = __builtin_bit_cast(uint32_t, a);
  ua += 0x7fffu + ((ua >> 16) & 1u);
  return (uint16_t)(ua >> 16);
}

// ---------------- prepass: x (f32) -> bf16 ----------------
__global__ void cvt_x_kernel(const float* __restrict__ x, uint16_t* __restrict__ xb) {
  int64_t e = ((int64_t)blockIdx.x * 256 + threadIdx.x) * 8;
  float4 f0 = *reinterpret_cast<const float4*>(x + e);
  float4 f1 = *reinterpret_cast<const float4*>(x + e + 4);
  uint4 u;
  u.x = pk_bf16(f0.x, f0.y);
  u.y = pk_bf16(f0.z, f0.w);
  u.z = pk_bf16(f1.x, f1.y);
  u.w = pk_bf16(f1.z, f1.w);
  *reinterpret_cast<uint4*>(xb + e) = u;
}

// ---------------- prepass: fragment-major B with Hamilton signs ----------------
// wtt layout: [nt(16)][kt(64)][wn(4)][fn(4)][kh(2)][lane(64)][8 bf16]
// lane l=(kg*16+rl): col = nt*256+wn*64+fn*16+rl, k = kt*64+kh*32+kg*8 .. +7
// One block per (kt, nt): reads a 64x256 f32 region of one W quadrant once.
__global__ void build_wt_tiled(const float* __restrict__ Wr, const float* __restrict__ Wi,
                               const float* __restrict__ Wj, const float* __restrict__ Wk,
                               uint16_t* __restrict__ wtt) {
  const int kt = blockIdx.x;   // 0..63
  const int nt = blockIdx.y;   // 0..15
  const int rc = kt >> 4, cc = nt >> 2;
  const int srcsel[16] = {0,1,2,3, 1,0,3,2, 2,3,0,1, 3,2,1,0};
  const float sgntab[16] = {1.f,1.f,1.f,1.f, -1.f,1.f,1.f,-1.f, -1.f,-1.f,1.f,1.f, -1.f,1.f,-1.f,1.f};
  const float* srcs[4] = {Wr, Wi, Wj, Wk};
  const float* W = srcs[srcsel[rc * 4 + cc]];
  const float sg = sgntab[rc * 4 + cc];
  const int tid = threadIdx.x;
#pragma unroll
  for (int p = 0; p < 8; ++p) {
    const int g = p * 256 + tid;            // 0..2047
    const int l = g & 63, fidx = g >> 6;    // fidx 0..31
    const int wn_ = fidx >> 3, fn = (fidx >> 1) & 3, kh = fidx & 1;
    const int kgq = l >> 4, rl_ = l & 15;
    const int col = nt * 256 + wn_ * 64 + fn * 16 + rl_;
    const int k0 = kt * 64 + kh * 32 + kgq * 8;
    const int nq = col & 1023, kq0 = k0 & 1023;
    const float* src = W + (int64_t)kq0 * 1024 + nq;
    float f0 = sg * src[0 * 1024], f1 = sg * src[1 * 1024];
    float f2 = sg * src[2 * 1024], f3 = sg * src[3 * 1024];
    float f4 = sg * src[4 * 1024], f5 = sg * src[5 * 1024];
    float f6 = sg * src[6 * 1024], f7 = sg * src[7 * 1024];
    uint4 u;
    u.x = pk_bf16(f0, f1); u.y = pk_bf16(f2, f3);
    u.z = pk_bf16(f4, f5); u.w = pk_bf16(f6, f7);
    *reinterpret_cast<uint4*>(wtt + ((int64_t)(nt * 64 + kt) * 2048 + g) * 8) = u;
  }
}

// ---------------- prepass: W^T [N][K] (fallback path only) ----------------
__global__ void build_wt_kernel(const float* __restrict__ Wr, const float* __restrict__ Wi,
                                const float* __restrict__ Wj, const float* __restrict__ Wk,
                                uint16_t* __restrict__ wt) {
  __shared__ float t[64][65];
  const int k0 = blockIdx.x * 64;
  const int n0 = blockIdx.y * 64;
  const int rc = k0 >> 10, cc = n0 >> 10;
  const int srcsel[16] = {0,1,2,3, 1,0,3,2, 2,3,0,1, 3,2,1,0};
  const float sgntab[16] = {1.f,1.f,1.f,1.f, -1.f,1.f,1.f,-1.f, -1.f,-1.f,1.f,1.f, -1.f,1.f,-1.f,1.f};
  const float* srcs[4] = {Wr, Wi, Wj, Wk};
  const float* W = srcs[srcsel[rc * 4 + cc]];
  const float sg = sgntab[rc * 4 + cc];
  const int kq0 = k0 & 1023, nq0 = n0 & 1023;
  const int tid = threadIdx.x;
  const int lr = tid >> 6;
  const int lc = tid & 63;
#pragma unroll
  for (int p = 0; p < 16; ++p) {
    int kl = p * 4 + lr;
    t[kl][lc] = W[(int64_t)(kq0 + kl) * 1024 + nq0 + lc];
  }
  __syncthreads();
  const int kb = (tid & 7) * 8;
#pragma unroll
  for (int p = 0; p < 2; ++p) {
    int nl = p * 32 + (tid >> 3);
    uint4 u;
    u.x = pk_bf16(sg * t[kb + 0][nl], sg * t[kb + 1][nl]);
    u.y = pk_bf16(sg * t[kb + 2][nl], sg * t[kb + 3][nl]);
    u.z = pk_bf16(sg * t[kb + 4][nl], sg * t[kb + 5][nl]);
    u.w = pk_bf16(sg * t[kb + 6][nl], sg * t[kb + 7][nl]);
    *reinterpret_cast<uint4*>(wt + (int64_t)(n0 + nl) * KDIM + k0 + kb) = u;
  }
}

// ================= v7: 256x256, B in regs (COALESCED), A-only LDS =================
// 8 waves 2Mx4N, per-wave C 128x64 (8x4 16x16x32 frags), BK=64.
// LDS: A only, 2 bufs x 32KB, linear gload_lds dest + pre-swizzled src, XOR read
//   (v6-proven, 0 conflicts). 160KB LDS traffic/K-tile (vs 256KB w/ B in LDS).
// B: fragment-major wtt layout -> each frag = one fully-coalesced 1KB
//   global_load_dwordx4 (inline asm, we control vmem issue order exactly).
// Sync per K-tile (v6-proven race-free): ISSUE(12 vmem) / vmcnt(12) / BAR /
//   COMPUTE (no internal barriers, waves skew, setprio on MFMA) / BAR.

#define SB __builtin_amdgcn_sched_barrier(0);
#define BAR __builtin_amdgcn_s_barrier();
#define WAITV(N) { SB asm volatile("s_waitcnt vmcnt(" #N ")"); SB }

#define BLOAD4(d0, d1, d2, d3, p)                                             \
  asm volatile("global_load_dwordx4 %0, %4, off\n\t"                          \
               "global_load_dwordx4 %1, %4, off offset:1024\n\t"              \
               "global_load_dwordx4 %2, %4, off offset:2048\n\t"              \
               "global_load_dwordx4 %3, %4, off offset:3072"                  \
               : "=&v"(d0), "=&v"(d1), "=&v"(d2), "=&v"(d3) : "v"(p));

// Issue one K-tile: 8 coalesced B loads (-> BD regs) + 4 A gload_lds. 12 vmem.
#define ISSUE_T(P, BD) {                                                      \
    BLOAD4(BD[0][0], BD[0][1], BD[1][0], BD[1][1], pB);                       \
    BLOAD4(BD[2][0], BD[2][1], BD[3][0], BD[3][1], pB2);                      \
    pB += 32768; pB2 += 32768;                                                \
    gload16(aS0, dstW + (P) * 32768);         aS0 += 64;                      \
    gload16(aS1, dstW + (P) * 32768 +  8192); aS1 += 64;                      \
    gload16(aS2, dstW + (P) * 32768 + 16384); aS2 += 64;                      \
    gload16(aS3, dstW + (P) * 32768 + 24576); aS3 += 64; }

// Compute one K-tile from A-buf parity P and B regs BD. No internal barriers.
#define COMPUTE(P, BD)                                                        \
  _Pragma("unroll")                                                           \
  for (int kh = 0; kh < 2; ++kh) {                                            \
    _Pragma("unroll")                                                         \
    for (int mh = 0; mh < 2; ++mh) {                                          \
      s16x8 afr[4];                                                           \
      _Pragma("unroll")                                                       \
      for (int f = 0; f < 4; ++f)                                             \
        afr[f] = *(const s16x8*)(Abuf + (P) * 32768 + (aoff[mh * 4 + f] ^ (kh * 64))); \
      __builtin_amdgcn_s_setprio(1);                                          \
      _Pragma("unroll")                                                       \
      for (int f = 0; f < 4; ++f)                                             \
        _Pragma("unroll")                                                     \
        for (int fn = 0; fn < 4; ++fn)                                        \
          acc[mh * 4 + f][fn] = __builtin_amdgcn_mfma_f32_16x16x32_bf16(      \
              afr[f], BD[fn][kh], acc[mh * 4 + f][fn], 0, 0, 0);              \
      __builtin_amdgcn_s_setprio(0);                                          \
    }                                                                         \
  }

__global__ __launch_bounds__(512, 2)
void qgemm10_kernel(const uint16_t* __restrict__ xb, const uint16_t* __restrict__ wtt,
                    const float* __restrict__ br, const float* __restrict__ bi,
                    const float* __restrict__ bj, const float* __restrict__ bk,
                    float* __restrict__ out) {
  __shared__ __align__(16) uint8_t Abuf[65536];
  const int tid = threadIdx.x;
  const int wid = tid >> 6, lane = tid & 63;
  const int kg = lane >> 4, rl = lane & 15;
  const int wm = wid >> 2, wn = wid & 3;

  // XCD-aware bijective swizzle (512 blocks % 8 == 0)
  const int bid = blockIdx.x;
  const int swz = (bid & 7) * 64 + (bid >> 3);
  const int tn = swz >> 5, tm = swz & 31;
  const int m0 = tm * 256, n0 = tn * 256;

  // ---- A staging (linear LDS dest, pre-swizzled global source) ----
  const int arow0 = tid >> 3;
  const int gch = (tid & 7) ^ (arow0 & 7);
  const uint16_t* aS0 = xb + (int64_t)(m0 + arow0) * KDIM + gch * 8;
  const uint16_t* aS1 = xb + (int64_t)(m0 + arow0 + 64) * KDIM + gch * 8;
  const uint16_t* aS2 = xb + (int64_t)(m0 + arow0 + 128) * KDIM + gch * 8;
  const uint16_t* aS3 = xb + (int64_t)(m0 + arow0 + 192) * KDIM + gch * 8;
  uint8_t* dstW = Abuf + wid * 1024;  // wave-uniform; HW appends lane*16

  // ---- B fragment-major pointers: coalesced 1KB per load ----
  // base = ((nt*64 + kt)*4 + wn)*8192 + lane*16 ; frag (fn,kh) at +(fn*2+kh)*1024
  const uint8_t* pB  = (const uint8_t*)wtt + ((int64_t)tn * 64 * 4 + wn) * 8192 + lane * 16;
  const uint8_t* pB2 = pB + 4096;

  // ---- A fragment read offsets (kh=0; kh=1 is ^64) ----
  int aoff[8];
#pragma unroll
  for (int q = 0; q < 8; ++q) {
    int r = wm * 128 + q * 16 + rl;  // q = mh*4+f
    aoff[q] = r * 128 + ((kg ^ (r & 7)) << 4);
  }

  accf_t acc[8][4] = {};
  s16x8 bA[4][2], bB[4][2];

  // prologue: tile 0 -> buf0/bA
  ISSUE_T(0, bA)

  for (int i = 0; i < 31; ++i) {
    ISSUE_T(1, bB)
    WAITV(12)
    BAR
    COMPUTE(0, bA)
    BAR
    ISSUE_T(0, bA)
    WAITV(12)
    BAR
    COMPUTE(1, bB)
    BAR
  }
  // tile 62 (buf0/bA), issuing 63 -> buf1/bB
  ISSUE_T(1, bB)
  WAITV(12)
  BAR
  COMPUTE(0, bA)
  BAR
  // tile 63 (buf1/bB)
  WAITV(0)
  BAR
  COMPUTE(1, bB)

  // epilogue: Hamilton bias + f32 store
  const float s_i[4] = {-1.f, 1.f, -1.f, 1.f};
  const float s_j[4] = {-1.f, 1.f, 1.f, -1.f};
  const float s_k[4] = {-1.f, -1.f, 1.f, 1.f};
  float bias[4];
#pragma unroll
  for (int fn = 0; fn < 4; ++fn) {
    int col = n0 + wn * 64 + fn * 16 + rl;
    int cc = col >> 10, nq = col & 1023;
    bias[fn] = br[nq] + s_i[cc] * bi[nq] + s_j[cc] * bj[nq] + s_k[cc] * bk[nq];
  }
#pragma unroll
  for (int fm = 0; fm < 8; ++fm) {
    int rowb = m0 + wm * 128 + fm * 16 + kg * 4;
#pragma unroll
    for (int r = 0; r < 4; ++r) {
      float* op = out + (int64_t)(rowb + r) * NDIM + n0 + wn * 64 + rl;
#pragma unroll
      for (int fn = 0; fn < 4; ++fn)
        op[fn * 16] = acc[fm][fn][r] + bias[fn];
    }
  }
}

// ---------------- fallback: R1 128x128 m97-structure GEMM (f32 x from global) ----------------
__global__ __launch_bounds__(256, 3)
void qgemm_kernel(const float* __restrict__ xf, const uint16_t* __restrict__ wt,
                  const float* __restrict__ br, const float* __restrict__ bi,
                  const float* __restrict__ bj, const float* __restrict__ bk,
                  float* __restrict__ out) {
  __shared__ __align__(16) uint16_t Alds[128 * 32];
  __shared__ __align__(16) uint16_t Blds[128 * 32];
  const int tid = threadIdx.x;
  const int wid = tid >> 6, lane = tid & 63;
  const int kg = lane >> 4, rl = lane & 15;
  const int bid = blockIdx.x;
  const int swz = (bid & 7) * 256 + (bid >> 3);
  const int tile_m = swz & 63;
  const int tile_n = swz >> 6;
  const int m0 = tile_m * 128, n0 = tile_n * 128;
  const int wr = wid >> 1, wc = wid & 1;
  const int e0 = tid * 8, e1 = (256 + tid) * 8;
  const int r0 = e0 >> 5, r1 = e1 >> 5;
  const int s0 = (e0 >> 3) & 3, s1 = (e1 >> 3) & 3;
  const int g0 = s0 ^ ((r0 >> 1) & 3);
  const int g1 = s1 ^ ((r1 >> 1) & 3);
  const uint16_t* bp0 = wt + (int64_t)(n0 + r0) * KDIM + g0 * 8;
  const uint16_t* bp1 = wt + (int64_t)(n0 + r1) * KDIM + g1 * 8;
  const float* af0 = xf + (int64_t)(m0 + r0) * KDIM + g0 * 8;
  const float* af1 = xf + (int64_t)(m0 + r1) * KDIM + g1 * 8;
  uint8_t* Ab = (uint8_t*)Alds;
  uint8_t* Bb = (uint8_t*)Blds;
  uint8_t* BbW0 = Bb + wid * 1024;
  uint8_t* BbW1 = Bb + 4096 + wid * 1024;
  uint8_t* aw0 = Ab + e0 * 2;
  uint8_t* aw1 = Ab + e1 * 2;
  int aoff[4], boff[4];
#pragma unroll
  for (int f = 0; f < 4; ++f) {
    int arow = wr * 64 + f * 16 + rl;
    aoff[f] = arow * 64 + ((kg ^ ((arow >> 1) & 3)) << 4);
    int bcol = wc * 64 + f * 16 + rl;
    boff[f] = bcol * 64 + ((kg ^ ((bcol >> 1) & 3)) << 4);
  }
  accf_t acc[4][4] = {};
  for (int kt = 0; kt < KDIM / 32; ++kt) {
    gload16(bp0, BbW0);
    gload16(bp1, BbW1);
    bp0 += 32; bp1 += 32;
    float4 fa = *reinterpret_cast<const float4*>(af0);
    float4 fb = *reinterpret_cast<const float4*>(af0 + 4);
    float4 fc = *reinterpret_cast<const float4*>(af1);
    float4 fd = *reinterpret_cast<const float4*>(af1 + 4);
    uint4 u0, u1;
    u0.x = pk_bf16(fa.x, fa.y); u0.y = pk_bf16(fa.z, fa.w);
    u0.z = pk_bf16(fb.x, fb.y); u0.w = pk_bf16(fb.z, fb.w);
    u1.x = pk_bf16(fc.x, fc.y); u1.y = pk_bf16(fc.z, fc.w);
    u1.z = pk_bf16(fd.x, fd.y); u1.w = pk_bf16(fd.z, fd.w);
    *reinterpret_cast<uint4*>(aw0) = u0;
    *reinterpret_cast<uint4*>(aw1) = u1;
    af0 += 32; af1 += 32;
    __syncthreads();
    s16x8 afr[4], bfr[4];
#pragma unroll
    for (int f = 0; f < 4; ++f) afr[f] = *reinterpret_cast<const s16x8*>(Ab + aoff[f]);
#pragma unroll
    for (int f = 0; f < 4; ++f) bfr[f] = *reinterpret_cast<const s16x8*>(Bb + boff[f]);
#pragma unroll
    for (int fm = 0; fm < 4; ++fm)
#pragma unroll
      for (int fn = 0; fn < 4; ++fn)
        acc[fm][fn] = __builtin_amdgcn_mfma_f32_16x16x32_bf16(afr[fm], bfr[fn], acc[fm][fn], 0, 0, 0);
    __syncthreads();
  }
  const float s_i[4] = {-1.f, 1.f, -1.f, 1.f};
  const float s_j[4] = {-1.f, 1.f, 1.f, -1.f};
  const float s_k[4] = {-1.f, -1.f, 1.f, 1.f};
  float bias[4];
#pragma unroll
  for (int fn = 0; fn < 4; ++fn) {
    int col = n0 + wc * 64 + fn * 16 + rl;
    int cc = col >> 10, nq = col & 1023;
    bias[fn] = br[nq] + s_i[cc] * bi[nq] + s_j[cc] * bj[nq] + s_k[cc] * bk[nq];
  }
#pragma unroll
  for (int fm = 0; fm < 4; ++fm) {
    int rowb = m0 + wr * 64 + fm * 16 + kg * 4;
#pragma unroll
    for (int r = 0; r < 4; ++r) {
      float* op = out + (int64_t)(rowb + r) * NDIM + n0 + wc * 64 + rl;
#pragma unroll
      for (int fn = 0; fn < 4; ++fn)
        op[fn * 16] = acc[fm][fn][r] + bias[fn];
    }
  }
}

// ---------------- emergency fallback (ws too small): naive f32 ----------------
__global__ void naive_q_kernel(const float* __restrict__ x,
                               const float* __restrict__ Wr, const float* __restrict__ Wi,
                               const float* __restrict__ Wj, const float* __restrict__ Wk,
                               const float* __restrict__ br, const float* __restrict__ bi,
                               const float* __restrict__ bj, const float* __restrict__ bk,
                               float* __restrict__ out) {
  const int n = blockIdx.x * 256 + threadIdx.x;
  const int m = blockIdx.y;
  const int cc = n >> 10, nq = n & 1023;
  const int srcsel[16] = {0,1,2,3, 1,0,3,2, 2,3,0,1, 3,2,1,0};
  const float sgntab[16] = {1.f,1.f,1.f,1.f, -1.f,1.f,1.f,-1.f, -1.f,-1.f,1.f,1.f, -1.f,1.f,-1.f,1.f};
  const float s_i[4] = {-1.f,1.f,-1.f,1.f}, s_j[4] = {-1.f,1.f,1.f,-1.f}, s_k[4] = {-1.f,-1.f,1.f,1.f};
  const float* srcs[4] = {Wr, Wi, Wj, Wk};
  float acc = br[nq] + s_i[cc] * bi[nq] + s_j[cc] * bj[nq] + s_k[cc] * bk[nq];
  for (int rc = 0; rc < 4; ++rc) {
    const float* W = srcs[srcsel[rc * 4 + cc]];
    const float sg = sgntab[rc * 4 + cc];
    const float* xp = x + (int64_t)m * KDIM + rc * 1024;
    const float* wp = W + nq;
    float a = 0.f;
    for (int kq = 0; kq < 1024; ++kq) a = fmaf(xp[kq], wp[(int64_t)kq * 1024], a);
    acc += sg * a;
  }
  out[(int64_t)m * NDIM + n] = acc;
}

extern "C" void kernel_launch(void* const* d_in, const int* in_sizes, int n_in,
                              void* d_out, int out_size, void* d_ws, size_t ws_size,
                              hipStream_t stream) {
  const float* x  = (const float*)d_in[0];
  const float* Wr = (const float*)d_in[1];
  const float* Wi = (const float*)d_in[2];
  const float* Wj = (const float*)d_in[3];
  const float* Wk = (const float*)d_in[4];
  const float* br = (const float*)d_in[5];
  const float* bi = (const float*)d_in[6];
  const float* bj = (const float*)d_in[7];
  const float* bk = (const float*)d_in[8];
  float* out = (float*)d_out;

  const size_t WT_BYTES = (size_t)NDIM * KDIM * 2;  // 33.5 MB
  const size_t XB_BYTES = (size_t)MDIM * KDIM * 2;  // 67 MB

  if (ws_size < WT_BYTES) {
    dim3 g(NDIM / 256, MDIM);
    naive_q_kernel<<<g, 256, 0, stream>>>(x, Wr, Wi, Wj, Wk, br, bi, bj, bk, out);
    return;
  }
  if (ws_size >= WT_BYTES + XB_BYTES) {
    uint16_t* wtt = (uint16_t*)d_ws;
    uint16_t* xbp = wtt + (size_t)NDIM * KDIM;
    build_wt_tiled<<<dim3(64, 16), 256, 0, stream>>>(Wr, Wi, Wj, Wk, wtt);
    cvt_x_kernel<<<(MDIM * (KDIM / 8)) / 256, 256, 0, stream>>>(x, xbp);
    qgemm10_kernel<<<512, 512, 0, stream>>>(xbp, wtt, br, bi, bj, bk, out);
  } else {
    uint16_t* wt = (uint16_t*)d_ws;
    build_wt_kernel<<<dim3(64, 64), 256, 0, stream>>>(Wr, Wi, Wj, Wk, wt);
    qgemm_kernel<<<2048, 256, 0, stream>>>(x, wt, br, bi, bj, bk, out);
  }
}